// Round 7
// baseline (40.648 us; speedup 1.0000x reference)
//
#include <hip/hip_runtime.h>
#include <math.h>

#define BB 32
#define TT 2048
#define CC 128
#define EE 256
#define LL 512
#define TYY 128
#define PP 24
#define KS 16           // K-splits per batch row (blocks per b)
#define KT 128          // t's per block
#define NST 4           // stages per block (32 t each)
#define PITCH 40        // halfwords per W_lds row (80B: 16B-aligned, 8 bank-groups)

// ws layout (floats):
//   pbuf  : [B*KS][P][256]   = 3145728  at 0        (j<128: sum, j>=128: cnt)
//   tpart : [B*KS*2][E]      = 262144   at 3145728
//   cbase : [B][P][C]        = 98304    at 3407872
#define WS_PBUF  0
#define WS_TPART 3145728
#define WS_CBASE 3407872

typedef __attribute__((ext_vector_type(8))) short bf16x8;
typedef __attribute__((ext_vector_type(4))) float f32x4;

__device__ __forceinline__ unsigned int pack_bf2(float a, float b) {
    unsigned int ua = __float_as_uint(a);
    unsigned int ub = __float_as_uint(b);
    ua = (ua + 0x7FFFu + ((ua >> 16) & 1u)) >> 16;           // RNE bf16 of a (low)
    ub = (ub + 0x7FFFu + ((ub >> 16) & 1u)) & 0xFFFF0000u;   // RNE bf16 of b (high)
    return ua | ub;
}

// ---------------------------------------------------------------------------
// K1: phase-bucket einsum via MFMA + fused sin-pool.
// grid = B*KS (512, 2 blocks/CU), block = 512 (8 waves), 1 barrier/stage.
// Per block: S[p][j] += onehot[p,t] * W[t,j] over its 128 t's (4 stages x 32),
// W[t][j<128] = bf16(X*M), W[t][128+c] = bf16(M). Double-buffered W_lds.
// Staging: thread (jc=tid&63, tp=tid>>6) loads 4 consecutive t's for columns
// {jc, jc+64} (coalesced 256B rows), packs pairs, 4x ds_write_b64 (~4-way).
// Compute: wave w -> p-half mt=w&1, j-tiles (w>>1)*4..+3; A one-hot in-reg.
// ---------------------------------------------------------------------------
__global__ __launch_bounds__(512, 4) void k_main(const float* __restrict__ ts,
                                                 const float* __restrict__ X,
                                                 const int*   __restrict__ M,
                                                 const float* __restrict__ tw,
                                                 const float* __restrict__ tbias,
                                                 float* __restrict__ pbuf,
                                                 float* __restrict__ tpart) {
    __shared__ unsigned short wbuf[2][256 * PITCH];   // 40 KB
    __shared__ float s_ts[KT];
    __shared__ int   s_p[KT];

    const int tid = threadIdx.x;
    const int blk = blockIdx.x;
    const int b   = blk >> 4;
    const int ks  = blk & 15;
    const int tB  = ks * KT;

    if (tid < KT) {
        const float v = ts[b * TT + tB + tid];
        s_ts[tid] = v;
        s_p[tid] = ((int)floorf(v)) % PP;          // ts >= 0
    }

    // staging roles
    const int jc = tid & 63;
    const int tp = tid >> 6;                       // 0..7
    float xa[4], xb[4]; int ma[4], mb[4];

    // compute roles
    const int wv   = tid >> 6;
    const int lane = tid & 63;
    const int mt   = wv & 1;
    const int jt0  = (wv >> 1) * 4;
    const int mrow = mt * 16 + (lane & 15);
    const int kg   = lane >> 4;                    // 0..3
    const int k0   = kg * 8;
    const int n16  = lane & 15;

    // sin roles
    const int se = tid & 255;
    const int sh = tid >> 8;                       // 0/1 t-half of each stage
    const float sw = tw[se];
    const float sb = tbias[se];
    float sacc = 0.0f;

    f32x4 acc[4];
#pragma unroll
    for (int jl = 0; jl < 4; ++jl) acc[jl] = (f32x4){0.f, 0.f, 0.f, 0.f};

    auto LOADS = [&](int s) {
#pragma unroll
        for (int k = 0; k < 4; ++k) {
            const int t = s * 32 + tp * 4 + k;
            const long r0 = ((long)(b * TT + tB + t)) * CC;
            xa[k] = X[r0 + jc];
            xb[k] = X[r0 + jc + 64];
            ma[k] = M[r0 + jc];
            mb[k] = M[r0 + jc + 64];
        }
    };

    auto WRITES = [&](int d) {
        unsigned int* wb = (unsigned int*)wbuf[d];
        const int th = tp * 2;                     // u32 slot for t = tp*4..+3
        const float a0 = ma[0] ? xa[0] : 0.0f, a1 = ma[1] ? xa[1] : 0.0f;
        const float a2 = ma[2] ? xa[2] : 0.0f, a3 = ma[3] ? xa[3] : 0.0f;
        const float c0 = mb[0] ? xb[0] : 0.0f, c1 = mb[1] ? xb[1] : 0.0f;
        const float c2 = mb[2] ? xb[2] : 0.0f, c3 = mb[3] ? xb[3] : 0.0f;
        *(uint2*)&wb[jc * 20 + th] =
            make_uint2(pack_bf2(a0, a1), pack_bf2(a2, a3));
        *(uint2*)&wb[(jc + 64) * 20 + th] =
            make_uint2(pack_bf2(c0, c1), pack_bf2(c2, c3));
        *(uint2*)&wb[(128 + jc) * 20 + th] =
            make_uint2((ma[0] ? 0x3F80u : 0u) | (ma[1] ? 0x3F800000u : 0u),
                       (ma[2] ? 0x3F80u : 0u) | (ma[3] ? 0x3F800000u : 0u));
        *(uint2*)&wb[(192 + jc) * 20 + th] =
            make_uint2((mb[0] ? 0x3F80u : 0u) | (mb[1] ? 0x3F800000u : 0u),
                       (mb[2] ? 0x3F80u : 0u) | (mb[3] ? 0x3F800000u : 0u));
    };

    auto COMPUTE = [&](int d, int s) {
        union { unsigned int u[4]; bf16x8 v; } au;
        const int tb0 = s * 32 + k0;
        const int4 pA = *(const int4*)&s_p[tb0];
        const int4 pB = *(const int4*)&s_p[tb0 + 4];
        au.u[0] = (pA.x == mrow ? 0x3F80u : 0u) | (pA.y == mrow ? 0x3F800000u : 0u);
        au.u[1] = (pA.z == mrow ? 0x3F80u : 0u) | (pA.w == mrow ? 0x3F800000u : 0u);
        au.u[2] = (pB.x == mrow ? 0x3F80u : 0u) | (pB.y == mrow ? 0x3F800000u : 0u);
        au.u[3] = (pB.z == mrow ? 0x3F80u : 0u) | (pB.w == mrow ? 0x3F800000u : 0u);
#pragma unroll
        for (int jl = 0; jl < 4; ++jl) {
            const int jrow = (jt0 + jl) * 16 + n16;
            const bf16x8 bv = *(const bf16x8*)&wbuf[d][jrow * PITCH + k0];
            acc[jl] = __builtin_amdgcn_mfma_f32_16x16x32_bf16(au.v, bv, acc[jl], 0, 0, 0);
        }
    };

    auto SINC = [&](int s) {
#pragma unroll
        for (int j = 0; j < 16; ++j) {
            const float v = fmaf(s_ts[s * 32 + sh * 16 + j], sw, sb);
            sacc += v + __sinf(v);
        }
    };

    LOADS(0);
    WRITES(0);
    LOADS(1);
    for (int s = 0; s < NST; ++s) {
        __syncthreads();                           // wbuf[s&1] + s_ts/s_p ready
        COMPUTE(s & 1, s);
        if (s + 1 < NST) WRITES((s + 1) & 1);
        if (s + 2 < NST) LOADS(s + 2);
        SINC(s);
    }

    tpart[((b * KS + ks) * 2 + sh) * EE + se] = sacc;

    // flush: C/D layout col=lane&15, row=(lane>>4)*4+reg
    float* pbb = pbuf + ((long)blk) * PP * 256;
#pragma unroll
    for (int jl = 0; jl < 4; ++jl) {
#pragma unroll
        for (int r = 0; r < 4; ++r) {
            const int p = mt * 16 + kg * 4 + r;
            if (p < PP)
                pbb[p * 256 + (jt0 + jl) * 16 + n16] = acc[jl][r];
        }
    }
}

// ---------------------------------------------------------------------------
// K2: reduce K-split partials -> c_base = sum / max(cnt,1).
// grid = B*P (768), block = 128 (c)
// ---------------------------------------------------------------------------
__global__ __launch_bounds__(128) void k_reduce(const float* __restrict__ pbuf,
                                                float* __restrict__ cbase) {
    const int b = blockIdx.x / PP;
    const int p = blockIdx.x % PP;
    const int c = threadIdx.x;
    float s = 0.0f, n = 0.0f;
#pragma unroll
    for (int k = 0; k < KS; ++k) {
        const float* pb = pbuf + ((long)(b * KS + k)) * PP * 256 + p * 256;
        s += pb[c];
        n += pb[128 + c];
    }
    cbase[(b * PP + p) * CC + c] = s / fmaxf(n, 1.0f);
}

// ---------------------------------------------------------------------------
// K3: decoder MLP + output scatter. grid = B*4 (128), block = 512.
// Each block redundantly computes pooled/h/Y for its b, writes 32 ty-rows.
// ---------------------------------------------------------------------------
__global__ __launch_bounds__(512) void k_tail(const float* __restrict__ tpart,
                                              const float* __restrict__ ce,
                                              const float* __restrict__ w1,
                                              const float* __restrict__ b1,
                                              const float* __restrict__ w2,
                                              const float* __restrict__ b2,
                                              const float* __restrict__ cbase,
                                              const float* __restrict__ yt,
                                              float* __restrict__ out) {
    __shared__ float s_pool[EE];
    __shared__ float s_h[LL];
    __shared__ float s_part[512];
    __shared__ float s_cb[PP * CC];
    __shared__ float s_y[CC];
    const int b = blockIdx.x >> 2;
    const int oct = blockIdx.x & 3;
    const int tid = threadIdx.x;

    {
        const int e = tid & 255;
        const int half = tid >> 8;
        float cm = 0.0f;
#pragma unroll 16
        for (int cc = half * 64; cc < half * 64 + 64; ++cc) cm += ce[cc * EE + e];
        s_part[tid] = cm;
    }
    __syncthreads();
    if (tid < EE) {
        float sp = 0.0f;
#pragma unroll
        for (int k = 0; k < KS * 2; ++k) sp += tpart[(b * KS * 2 + k) * EE + tid];
        s_pool[tid] = sp * (1.0f / TT)
                    + (s_part[tid] + s_part[tid + 256]) * (1.0f / CC);
    }
    __syncthreads();

    float hacc = b1[tid];
#pragma unroll 16
    for (int e = 0; e < EE; ++e) hacc = fmaf(s_pool[e], w1[e * LL + tid], hacc);
    s_h[tid] = fmaxf(hacc, 0.0f);
    __syncthreads();

    {
        const int c = tid & 127;
        const int q = tid >> 7;
        float y = 0.0f;
#pragma unroll 16
        for (int l = q * 128; l < q * 128 + 128; ++l) y = fmaf(s_h[l], w2[l * CC + c], y);
        s_part[tid] = y;
    }
    for (int i = tid; i < PP * CC; i += 512) s_cb[i] = cbase[b * PP * CC + i];
    __syncthreads();
    if (tid < CC)
        s_y[tid] = b2[tid] + s_part[tid] + s_part[tid + 128]
                 + s_part[tid + 256] + s_part[tid + 384];
    __syncthreads();

    for (int i = tid; i < 32 * CC; i += 512) {
        const int ty = oct * 32 + (i >> 7);
        const int c = i & 127;
        const float v = yt[b * TYY + ty];
        int p = ((int)floorf(v)) % PP; if (p < 0) p += PP;
        out[((long)(b * TYY + ty)) * CC + c] = s_y[c] + s_cb[p * CC + c];
    }
}

extern "C" void kernel_launch(void* const* d_in, const int* in_sizes, int n_in,
                              void* d_out, int out_size, void* d_ws, size_t ws_size,
                              hipStream_t stream) {
    const float* ts   = (const float*)d_in[0];
    const float* X    = (const float*)d_in[1];
    const int*   M    = (const int*)  d_in[2];
    const float* yt   = (const float*)d_in[3];
    const float* tw   = (const float*)d_in[4];
    const float* tb   = (const float*)d_in[5];
    const float* ce   = (const float*)d_in[6];
    const float* w1   = (const float*)d_in[7];
    const float* b1   = (const float*)d_in[8];
    const float* w2   = (const float*)d_in[9];
    const float* b2   = (const float*)d_in[10];
    float* out = (float*)d_out;

    float* ws    = (float*)d_ws;
    float* pbuf  = ws + WS_PBUF;
    float* tpart = ws + WS_TPART;
    float* cbase = ws + WS_CBASE;

    k_main<<<BB * KS, 512, 0, stream>>>(ts, X, M, tw, tb, pbuf, tpart);
    k_reduce<<<BB * PP, 128, 0, stream>>>(pbuf, cbase);
    k_tail<<<BB * 4, 512, 0, stream>>>(tpart, ce, w1, b1, w2, b2, cbase, yt, out);
}

// Round 8
// 35.774 us; speedup vs baseline: 1.1362x; 1.1362x over previous
//
#include <hip/hip_runtime.h>
#include <math.h>

#define BB 32
#define TT 2048
#define CC 128
#define EE 256
#define LL 512
#define TYY 128
#define PP 24
#define KS 8            // K-splits per batch row (blocks per b)
#define KT 256          // t's per block
#define NST 8           // stages per block (32 t each)
#define PITCH 40        // halfwords per W_lds row (80B: 16B-aligned)

// ws layout (floats):
//   pbuf  : [B*KS][P][256]   = 1572864  at 0        (j<128: sum, j>=128: cnt)
//   tpart : [B*KS*2][E]      = 131072   at 1572864
//   cbase : [B][P][C]        = 98304    at 1703936
#define WS_PBUF  0
#define WS_TPART 1572864
#define WS_CBASE 1703936

typedef __attribute__((ext_vector_type(8))) short bf16x8;
typedef __attribute__((ext_vector_type(4))) float f32x4;

__device__ __forceinline__ unsigned int pack_bf2(float a, float b) {
    unsigned int ua = __float_as_uint(a);
    unsigned int ub = __float_as_uint(b);
    ua = (ua + 0x7FFFu + ((ua >> 16) & 1u)) >> 16;           // RNE bf16 of a (low)
    ub = (ub + 0x7FFFu + ((ub >> 16) & 1u)) & 0xFFFF0000u;   // RNE bf16 of b (high)
    return ua | ub;
}

// ---------------------------------------------------------------------------
// K1: phase-bucket einsum via MFMA + fused sin-pool.
// grid = B*KS (256), block = 512 (8 waves).
// Stage order is barrier -> ISSUE LOADS(s+2) -> SINC -> COMPUTE(s) ->
// WRITES(s+1): the vmcnt(0) drain at the *next* barrier lands a full stage
// (~2500 cy) after load issue, so HBM latency hides under compute.
// Two register parity sets; stage loop fully unrolled (compile-time indices).
// ---------------------------------------------------------------------------
__global__ __launch_bounds__(512) void k_main(const float* __restrict__ ts,
                                              const float* __restrict__ X,
                                              const int*   __restrict__ M,
                                              const float* __restrict__ tw,
                                              const float* __restrict__ tbias,
                                              float* __restrict__ pbuf,
                                              float* __restrict__ tpart) {
    __shared__ unsigned short wbuf[2][256 * PITCH];   // 40 KB
    __shared__ float s_ts[KT];
    __shared__ int   s_p[KT];

    const int tid = threadIdx.x;
    const int blk = blockIdx.x;
    const int b   = blk >> 3;
    const int ks  = blk & 7;
    const int tB  = ks * KT;

    if (tid < KT) {
        const float v = ts[b * TT + tB + tid];
        s_ts[tid] = v;
        s_p[tid] = ((int)floorf(v)) % PP;          // ts >= 0
    }

    // staging roles
    const int jc = tid & 63;
    const int tp = tid >> 6;                       // 0..7
    float xr0[2][2], xr1[2][2], xr2[2][2], xr3[2][2];   // [parity][it]
    int   mr0[2][2], mr1[2][2], mr2[2][2], mr3[2][2];

    // compute roles
    const int wv   = tid >> 6;
    const int lane = tid & 63;
    const int mt   = wv & 1;
    const int jt0  = (wv >> 1) * 4;
    const int mrow = mt * 16 + (lane & 15);
    const int kg   = lane >> 4;                    // 0..3
    const int k0   = kg * 8;
    const int n16  = lane & 15;

    // sin roles
    const int se = tid & 255;
    const int sh = tid >> 8;
    const float sw = tw[se];
    const float sb = tbias[se];
    float sacc = 0.0f;

    f32x4 acc[4];
#pragma unroll
    for (int jl = 0; jl < 4; ++jl) acc[jl] = (f32x4){0.f, 0.f, 0.f, 0.f};

    auto LOADS = [&](int s) {
        const int pr = s & 1;
#pragma unroll
        for (int it = 0; it < 2; ++it) {
            const int ttv = it * 16 + tp * 2;
            const long r0 = ((long)(b * TT + tB + s * 32 + ttv)) * CC;
            xr0[pr][it] = X[r0 + jc];
            xr1[pr][it] = X[r0 + jc + 64];
            xr2[pr][it] = X[r0 + CC + jc];
            xr3[pr][it] = X[r0 + CC + jc + 64];
            mr0[pr][it] = M[r0 + jc];
            mr1[pr][it] = M[r0 + jc + 64];
            mr2[pr][it] = M[r0 + CC + jc];
            mr3[pr][it] = M[r0 + CC + jc + 64];
        }
    };

    auto WRITES = [&](int s) {                     // stage s -> wbuf[s&1], regs parity s&1
        const int pr = s & 1;
        unsigned int* wb = (unsigned int*)wbuf[pr];
#pragma unroll
        for (int it = 0; it < 2; ++it) {
            const int ttv = it * 16 + tp * 2;
            const int th = ttv >> 1;
            const float xm00 = mr0[pr][it] ? xr0[pr][it] : 0.0f;
            const float xm10 = mr2[pr][it] ? xr2[pr][it] : 0.0f;
            const float xm01 = mr1[pr][it] ? xr1[pr][it] : 0.0f;
            const float xm11 = mr3[pr][it] ? xr3[pr][it] : 0.0f;
            wb[jc * 20 + th]         = pack_bf2(xm00, xm10);
            wb[(jc + 64) * 20 + th]  = pack_bf2(xm01, xm11);
            wb[(128 + jc) * 20 + th] = (mr0[pr][it] ? 0x3F80u : 0u) | (mr2[pr][it] ? 0x3F800000u : 0u);
            wb[(192 + jc) * 20 + th] = (mr1[pr][it] ? 0x3F80u : 0u) | (mr3[pr][it] ? 0x3F800000u : 0u);
        }
    };

    auto COMPUTE = [&](int s) {
        union { unsigned int u[4]; bf16x8 v; } au;
        const int tb0 = s * 32 + k0;
        const int4 pA = *(const int4*)&s_p[tb0];
        const int4 pB = *(const int4*)&s_p[tb0 + 4];
        au.u[0] = (pA.x == mrow ? 0x3F80u : 0u) | (pA.y == mrow ? 0x3F800000u : 0u);
        au.u[1] = (pA.z == mrow ? 0x3F80u : 0u) | (pA.w == mrow ? 0x3F800000u : 0u);
        au.u[2] = (pB.x == mrow ? 0x3F80u : 0u) | (pB.y == mrow ? 0x3F800000u : 0u);
        au.u[3] = (pB.z == mrow ? 0x3F80u : 0u) | (pB.w == mrow ? 0x3F800000u : 0u);
#pragma unroll
        for (int jl = 0; jl < 4; ++jl) {
            const int jrow = (jt0 + jl) * 16 + n16;
            const bf16x8 bv = *(const bf16x8*)&wbuf[s & 1][jrow * PITCH + k0];
            acc[jl] = __builtin_amdgcn_mfma_f32_16x16x32_bf16(au.v, bv, acc[jl], 0, 0, 0);
        }
    };

    auto SINC = [&](int s) {
#pragma unroll
        for (int j = 0; j < 16; ++j) {
            const float v = fmaf(s_ts[s * 32 + sh * 16 + j], sw, sb);
            sacc += v + __sinf(v);
        }
    };

    LOADS(0);
    WRITES(0);                                     // wbuf[0] (pre-barrier, fine)
    LOADS(1);
#pragma unroll
    for (int s = 0; s < NST; ++s) {
        __syncthreads();                           // wbuf[s&1] ready; drains prev prefetch
        if (s + 2 < NST) LOADS(s + 2);             // issue EARLY: full-stage overlap
        SINC(s);
        COMPUTE(s);
        if (s + 1 < NST) WRITES(s + 1);
    }

    tpart[((b * KS + ks) * 2 + sh) * EE + se] = sacc;

    // flush: C/D layout col=lane&15, row=(lane>>4)*4+reg
    float* pbb = pbuf + ((long)blk) * PP * 256;
#pragma unroll
    for (int jl = 0; jl < 4; ++jl) {
#pragma unroll
        for (int r = 0; r < 4; ++r) {
            const int p = mt * 16 + kg * 4 + r;
            if (p < PP)
                pbb[p * 256 + (jt0 + jl) * 16 + n16] = acc[jl][r];
        }
    }
}

// ---------------------------------------------------------------------------
// K2: reduce K-split partials -> c_base = sum / max(cnt,1).
// grid = B*P (768), block = 128 (c)
// ---------------------------------------------------------------------------
__global__ __launch_bounds__(128) void k_reduce(const float* __restrict__ pbuf,
                                                float* __restrict__ cbase) {
    const int b = blockIdx.x / PP;
    const int p = blockIdx.x % PP;
    const int c = threadIdx.x;
    float s = 0.0f, n = 0.0f;
#pragma unroll
    for (int k = 0; k < KS; ++k) {
        const float* pb = pbuf + ((long)(b * KS + k)) * PP * 256 + p * 256;
        s += pb[c];
        n += pb[128 + c];
    }
    cbase[(b * PP + p) * CC + c] = s / fmaxf(n, 1.0f);
}

// ---------------------------------------------------------------------------
// K3: decoder MLP + output scatter. grid = B (32), block = 1024.
// No redundant weight reads (29 MB total); dot loops split across thread
// groups with LDS partial reduction for parallelism.
// ---------------------------------------------------------------------------
__global__ __launch_bounds__(1024) void k_tail(const float* __restrict__ tpart,
                                               const float* __restrict__ ce,
                                               const float* __restrict__ w1,
                                               const float* __restrict__ b1,
                                               const float* __restrict__ w2,
                                               const float* __restrict__ b2,
                                               const float* __restrict__ cbase,
                                               const float* __restrict__ yt,
                                               float* __restrict__ out) {
    __shared__ float s_pool[EE];
    __shared__ float s_h[LL];
    __shared__ float s_part[1024];
    __shared__ float s_cb[PP * CC];
    __shared__ float s_y[CC];
    const int b = blockIdx.x;
    const int tid = threadIdx.x;

    // stage cbase slice early (overlaps the MLP phases)
    for (int i = tid; i < PP * CC; i += 1024) s_cb[i] = cbase[b * PP * CC + i];

    // channel-embed column mean: e = tid&255, quarter q sums 32 c's
    {
        const int e = tid & 255;
        const int q = tid >> 8;
        float cm = 0.0f;
#pragma unroll
        for (int cc = q * 32; cc < q * 32 + 32; ++cc) cm += ce[cc * EE + e];
        s_part[tid] = cm;
    }
    __syncthreads();
    if (tid < EE) {
        float sp = 0.0f;
#pragma unroll
        for (int k = 0; k < KS * 2; ++k) sp += tpart[(b * KS * 2 + k) * EE + tid];
        s_pool[tid] = sp * (1.0f / TT)
                    + (s_part[tid] + s_part[tid + 256] + s_part[tid + 512]
                       + s_part[tid + 768]) * (1.0f / CC);
    }
    __syncthreads();

    // h: l = tid&511, half hh over e
    {
        const int l = tid & 511;
        const int hh = tid >> 9;
        float ha = 0.0f;
#pragma unroll 16
        for (int e = hh * 128; e < hh * 128 + 128; ++e)
            ha = fmaf(s_pool[e], w1[e * LL + l], ha);
        s_part[tid] = ha;
    }
    __syncthreads();
    if (tid < LL)
        s_h[tid] = fmaxf(b1[tid] + s_part[tid] + s_part[tid + 512], 0.0f);
    __syncthreads();

    // y: c = tid&127, oct q8 over l (64 each)
    {
        const int c = tid & 127;
        const int q8 = tid >> 7;
        float y = 0.0f;
#pragma unroll 16
        for (int l = q8 * 64; l < q8 * 64 + 64; ++l)
            y = fmaf(s_h[l], w2[l * CC + c], y);
        s_part[tid] = y;
    }
    __syncthreads();
    if (tid < CC) {
        float y = b2[tid];
#pragma unroll
        for (int i = 0; i < 8; ++i) y += s_part[tid + 128 * i];
        s_y[tid] = y;
    }
    __syncthreads();

    for (int i = tid; i < TYY * CC; i += 1024) {
        const int ty = i >> 7;
        const int c = i & 127;
        const float v = yt[b * TYY + ty];
        int p = ((int)floorf(v)) % PP; if (p < 0) p += PP;
        out[((long)(b * TYY + ty)) * CC + c] = s_y[c] + s_cb[p * CC + c];
    }
}

extern "C" void kernel_launch(void* const* d_in, const int* in_sizes, int n_in,
                              void* d_out, int out_size, void* d_ws, size_t ws_size,
                              hipStream_t stream) {
    const float* ts   = (const float*)d_in[0];
    const float* X    = (const float*)d_in[1];
    const int*   M    = (const int*)  d_in[2];
    const float* yt   = (const float*)d_in[3];
    const float* tw   = (const float*)d_in[4];
    const float* tb   = (const float*)d_in[5];
    const float* ce   = (const float*)d_in[6];
    const float* w1   = (const float*)d_in[7];
    const float* b1   = (const float*)d_in[8];
    const float* w2   = (const float*)d_in[9];
    const float* b2   = (const float*)d_in[10];
    float* out = (float*)d_out;

    float* ws    = (float*)d_ws;
    float* pbuf  = ws + WS_PBUF;
    float* tpart = ws + WS_TPART;
    float* cbase = ws + WS_CBASE;

    k_main<<<BB * KS, 512, 0, stream>>>(ts, X, M, tw, tb, pbuf, tpart);
    k_reduce<<<BB * PP, 128, 0, stream>>>(pbuf, cbase);
    k_tail<<<BB, 1024, 0, stream>>>(tpart, ce, w1, b1, w2, b2, cbase, yt, out);
}